// Round 3
// baseline (6212.962 us; speedup 1.0000x reference)
//
#include <hip/hip_runtime.h>
#include <cstdint>

#define NUM_CLASSES 20
#define KSEL 5
#define M_PTS 10000
#define C_DIM 256
#define HW 16384
#define NQ 32           // queries per block
#define BJ 256          // j per tile (== blockDim so thread t owns norm of j0+t)
#define BK 16           // channels per LDS stage
#define NCK (C_DIM/BK)  // 16
#define BROW 264        // Bs row: 64 swizzled f4 slots + 2 pad f4
#define NJT 40          // 40*256 = 10240 >= 10000
#define INFV 1e30f

// Block: 32 queries x all M. 256 threads (4 waves).
// Thread t: qg = t>>5 (4 rows qg*4..+3), jg = t&31 (8 cols jg*8..+7).
// Bs is [c][j] with XOR f4-swizzle: logical f4 f stored at slot f ^ ((f>>3)&7)
// -> lane-stride-32B reads spread over all 8 bank-quads (BW floor, no 8-way).
__global__ __launch_bounds__(256, 4) void knn_main(
    const float* __restrict__ x, const float* __restrict__ mx,
    const int* __restrict__ my, float* __restrict__ out)
{
  __shared__ union SMem {
    struct { float As[BK][NQ]; float Bs[BK][BROW]; float mnS[BJ]; } m;  // 19.9 KB
    struct { float Lv[32 * NQ * KSEL]; int Lj[32 * NQ * KSEL]; } e;     // 40 KB
  } sm;

  const int t  = threadIdx.x;
  const int qg = t >> 5;
  const int jg = t & 31;

  const int qflat = blockIdx.x * NQ;
  const int bb    = qflat >> 14;
  const int hw0   = qflat & (HW - 1);
  const float* xbase = x + (size_t)bb * C_DIM * HW + hw0;   // [c][q] at c*HW+q

  // B swizzle columns: write slot for j=t, read slots for logical f4 {2jg, 2jg+1}
  const int wcol = (((t >> 2) ^ ((t >> 5) & 7)) << 2) + (t & 3);
  const int p0   = (2 * jg) ^ ((jg >> 2) & 7);
  const int rc0  = p0 << 2;
  const int rc1  = (p0 ^ 1) << 2;

  float lv[4][KSEL]; int lj[4][KSEL]; float thr[4];
#pragma unroll
  for (int r = 0; r < 4; ++r) {
    thr[r] = INFV;
#pragma unroll
    for (int e = 0; e < KSEL; ++e) { lv[r][e] = INFV; lj[r][e] = 0x7fffffff; }
  }

  // ---- software-pipelined staging regs: stage (jt, ckt) held in va/vb ----
  float4 va; float4 vb[4];
  if (t < 128) va = *(const float4*)(xbase + (size_t)(t >> 3) * HW + (t & 7) * 4);
  {
    const int g = (t < M_PTS) ? t : (M_PTS - 1);
    const float4* r4 = (const float4*)(mx + (size_t)g * C_DIM);
    vb[0] = r4[0]; vb[1] = r4[1]; vb[2] = r4[2]; vb[3] = r4[3];
  }

  for (int jt = 0; jt < NJT; ++jt) {
    const int j0 = jt * BJ;
    __syncthreads();                    // prev tile's mnS readers done

    // ||m||^2 for j0+t (L2-resident; ~3% extra FMA)
    {
      const int j = j0 + t;
      const int g = (j < M_PTS) ? j : (M_PTS - 1);
      const float4* r4 = (const float4*)(mx + (size_t)g * C_DIM);
      float s = 0.f;
#pragma unroll 8
      for (int k = 0; k < C_DIM / 4; ++k) {
        float4 v = r4[k];
        s = fmaf(v.x, v.x, s); s = fmaf(v.y, v.y, s);
        s = fmaf(v.z, v.z, s); s = fmaf(v.w, v.w, s);
      }
      sm.m.mnS[t] = (j < M_PTS) ? s : INFV;
    }

    float acc[4][8];
#pragma unroll
    for (int r = 0; r < 4; ++r)
#pragma unroll
      for (int s = 0; s < 8; ++s) acc[r][s] = 0.f;

    for (int ckt = 0; ckt < NCK; ++ckt) {
      __syncthreads();                  // prev stage's LDS readers done
      if (t < 128) *(float4*)&sm.m.As[t >> 3][(t & 7) * 4] = va;
      {
        const float* vbf = (const float*)vb;
#pragma unroll
        for (int c = 0; c < BK; ++c) sm.m.Bs[c][wcol] = vbf[c];
      }
      __syncthreads();                  // staging visible

      // prefetch next stage (overlaps FMA below)
      {
        int nk = ckt + 1, njt = jt;
        if (nk == NCK) { nk = 0; njt = (jt + 1 < NJT) ? (jt + 1) : 0; }
        const int c0n = nk * BK, j0n = njt * BJ;
        if (t < 128) va = *(const float4*)(xbase + (size_t)(c0n + (t >> 3)) * HW + (t & 7) * 4);
        int j = j0n + t;
        const int g = (j < M_PTS) ? j : (M_PTS - 1);
        const float4* r4 = (const float4*)(mx + (size_t)g * C_DIM + c0n);
        vb[0] = r4[0]; vb[1] = r4[1]; vb[2] = r4[2]; vb[3] = r4[3];
      }

#pragma unroll
      for (int ck = 0; ck < BK; ++ck) {
        const float4 a  = *(const float4*)&sm.m.As[ck][qg * 4];   // 2 addrs/wave: broadcast
        const float4 b0 = *(const float4*)&sm.m.Bs[ck][rc0];      // swizzled, 4-way floor
        const float4 b1 = *(const float4*)&sm.m.Bs[ck][rc1];
        const float av_[4] = {a.x, a.y, a.z, a.w};
        const float bw_[8] = {b0.x, b0.y, b0.z, b0.w, b1.x, b1.y, b1.z, b1.w};
#pragma unroll
        for (int r = 0; r < 4; ++r)
#pragma unroll
          for (int s = 0; s < 8; ++s)
            acc[r][s] = fmaf(av_[r], bw_[s], acc[r][s]);
      }
    }

    // selection: score = ||m||^2 - 2*dot; increasing-j arrival + strict '<'
    // == top_k lower-index tie-break. (j>=M_PTS: mnS=1e30, fmaf absorbs -> never inserted)
    const float4 mn0 = *(const float4*)&sm.m.mnS[jg * 8];
    const float4 mn1 = *(const float4*)&sm.m.mnS[jg * 8 + 4];
    const float mnr[8] = {mn0.x, mn0.y, mn0.z, mn0.w, mn1.x, mn1.y, mn1.z, mn1.w};
#pragma unroll
    for (int r = 0; r < 4; ++r) {
      float th = thr[r];
#pragma unroll
      for (int s = 0; s < 8; ++s) {
        const float sc = fmaf(-2.f, acc[r][s], mnr[s]);
        if (sc < th) {
          const int jidx = j0 + jg * 8 + s;
          const float v0 = lv[r][0], v1 = lv[r][1], v2 = lv[r][2], v3 = lv[r][3];
          const int   i0 = lj[r][0], i1 = lj[r][1], i2 = lj[r][2], i3 = lj[r][3];
          const bool c0 = sc < v0, c1 = sc < v1, c2 = sc < v2, c3 = sc < v3;
          lv[r][4] = c3 ? v3 : sc;               lj[r][4] = c3 ? i3 : jidx;
          lv[r][3] = c3 ? (c2 ? v2 : sc) : v3;   lj[r][3] = c3 ? (c2 ? i2 : jidx) : i3;
          lv[r][2] = c2 ? (c1 ? v1 : sc) : v2;   lj[r][2] = c2 ? (c1 ? i1 : jidx) : i2;
          lv[r][1] = c1 ? (c0 ? v0 : sc) : v1;   lj[r][1] = c1 ? (c0 ? i0 : jidx) : i1;
          lv[r][0] = c0 ? sc : v0;               lj[r][0] = c0 ? jidx : i0;
          th = lv[r][4];
        }
      }
      thr[r] = th;
    }
  }

  // ---- epilogue: dump lists, per-query serial merge, fp64 re-rank, vote ----
  __syncthreads();                      // main loop done; overlay Bs with lists
#pragma unroll
  for (int r = 0; r < 4; ++r) {
    const int q = qg * 4 + r;
    const int base = (jg * NQ + q) * KSEL;      // [jg][q][e]: merge-reads stride 5 dw
#pragma unroll
    for (int e = 0; e < KSEL; ++e) { sm.e.Lv[base + e] = lv[r][e]; sm.e.Lj[base + e] = lj[r][e]; }
  }
  __syncthreads();

  if (t < NQ) {                         // one thread per query
    float bv[8]; int bj2[8];
#pragma unroll
    for (int k = 0; k < 8; ++k) { bv[k] = INFV; bj2[k] = 0x7fffffff; }
    for (int p = 0; p < 32; ++p) {
      const int base = (p * NQ + t) * KSEL;
#pragma unroll
      for (int e = 0; e < KSEL; ++e) {
        const float v = sm.e.Lv[base + e];
        const int  j = sm.e.Lj[base + e];
        if (v < bv[7] || (v == bv[7] && j < bj2[7])) {
          int pos = 7;
          while (pos > 0 && (bv[pos - 1] > v || (bv[pos - 1] == v && bj2[pos - 1] > j))) {
            bv[pos] = bv[pos - 1]; bj2[pos] = bj2[pos - 1]; --pos;
          }
          bv[pos] = v; bj2[pos] = j;
        }
      }
    }
    // fp64 exact distances for the 8 candidates (x reads coalesced across lanes)
    const float *m0 = mx + (size_t)bj2[0] * C_DIM, *m1 = mx + (size_t)bj2[1] * C_DIM;
    const float *m2 = mx + (size_t)bj2[2] * C_DIM, *m3 = mx + (size_t)bj2[3] * C_DIM;
    const float *m4 = mx + (size_t)bj2[4] * C_DIM, *m5 = mx + (size_t)bj2[5] * C_DIM;
    const float *m6 = mx + (size_t)bj2[6] * C_DIM, *m7 = mx + (size_t)bj2[7] * C_DIM;
    const float* xq = xbase + t;
    double d0 = 0, d1 = 0, d2 = 0, d3 = 0, d4 = 0, d5 = 0, d6 = 0, d7 = 0;
#pragma unroll 4
    for (int c = 0; c < C_DIM; ++c) {
      const double xv = (double)xq[(size_t)c * HW];
      double dd;
      dd = xv - (double)m0[c]; d0 = fma(dd, dd, d0);
      dd = xv - (double)m1[c]; d1 = fma(dd, dd, d1);
      dd = xv - (double)m2[c]; d2 = fma(dd, dd, d2);
      dd = xv - (double)m3[c]; d3 = fma(dd, dd, d3);
      dd = xv - (double)m4[c]; d4 = fma(dd, dd, d4);
      dd = xv - (double)m5[c]; d5 = fma(dd, dd, d5);
      dd = xv - (double)m6[c]; d6 = fma(dd, dd, d6);
      dd = xv - (double)m7[c]; d7 = fma(dd, dd, d7);
    }
    const double dv[8] = {d0, d1, d2, d3, d4, d5, d6, d7};
    const int    jv[8] = {bj2[0], bj2[1], bj2[2], bj2[3], bj2[4], bj2[5], bj2[6], bj2[7]};
    int lab[KSEL]; unsigned used = 0;
#pragma unroll
    for (int n = 0; n < KSEL; ++n) {
      double bd = 1e300; int bjx = 0x7fffffff; int bk = 0;
#pragma unroll
      for (int k = 0; k < 8; ++k) {
        const bool avail = ((used >> k) & 1u) == 0u;
        if (avail && (dv[k] < bd || (dv[k] == bd && jv[k] < bjx))) {
          bd = dv[k]; bjx = jv[k]; bk = k;
        }
      }
      used |= (1u << bk);
      lab[n] = my[bjx];
    }
    // mode vote; tie -> smallest class id
    int bestLab = NUM_CLASSES, bestCnt = 0;
#pragma unroll
    for (int a = 0; a < KSEL; ++a) {
      int cnt = 0;
#pragma unroll
      for (int b2 = 0; b2 < KSEL; ++b2) cnt += (lab[b2] == lab[a]) ? 1 : 0;
      if (cnt > bestCnt || (cnt == bestCnt && lab[a] < bestLab)) { bestCnt = cnt; bestLab = lab[a]; }
    }
    // one-hot write, coalesced per class plane (each q written exactly once)
    float* ob = out + (size_t)bb * NUM_CLASSES * HW + hw0 + t;
#pragma unroll
    for (int cls = 0; cls < NUM_CLASSES; ++cls)
      ob[(size_t)cls * HW] = (cls == bestLab) ? 1.0f : 0.0f;
  }
}

extern "C" void kernel_launch(void* const* d_in, const int* in_sizes, int n_in,
                              void* d_out, int out_size, void* d_ws, size_t ws_size,
                              hipStream_t stream) {
  (void)in_sizes; (void)n_in; (void)d_ws; (void)ws_size; (void)out_size;
  const float* x  = (const float*)d_in[0];
  const float* mx = (const float*)d_in[2];   // d_in[1] (y) unused by reference
  const int*   my = (const int*)d_in[3];
  float* out = (float*)d_out;
  knn_main<<<32768 / NQ, 256, 0, stream>>>(x, mx, my, out);
}